// Round 11
// baseline (490.520 us; speedup 1.0000x reference)
//
#include <hip/hip_runtime.h>
#include <stdint.h>

#define SEQ     1024
#define DPROJ   4480
// proj columns: z=0, x=2048, Bp=4096, Cp=4224, dd_dt=4352, dd_A=4384, trap=4416, ang=4448

typedef __attribute__((ext_vector_type(8))) short short8;
typedef __attribute__((ext_vector_type(4))) float f4;

__device__ __forceinline__ short f2b(float f){
  union { float f; uint32_t u; } v; v.f = f;
  uint32_t r = (v.u + 0x7fffu + ((v.u >> 16) & 1u)) >> 16;
  return (short)(uint16_t)r;
}
__device__ __forceinline__ float b2f(uint16_t u){
  union { uint32_t u; float f; } v; v.u = ((uint32_t)u) << 16; return v.f;
}
__device__ __forceinline__ uint32_t pack2(float lo, float hi){
  return (uint32_t)(uint16_t)f2b(lo) | ((uint32_t)(uint16_t)f2b(hi) << 16);
}
__device__ __forceinline__ float softplus_f(float x){
  return x > 20.f ? x : log1pf(__expf(x));
}
__device__ __forceinline__ void gload_lds16(const short* g, short* l){
  __builtin_amdgcn_global_load_lds((const __attribute__((address_space(1))) void*)g,
                                   (__attribute__((address_space(3))) void*)l, 16, 0, 0);
}

// ---- manual grid barrier: one fresh counter per phase (no reset; init kernel zeroes) ----
// All 256 blocks are co-resident by construction (grid=256=CUs, LDS 38.4K, VGPR<=256 via
// launch_bounds(256,2) -> 2 blocks/CU capacity), so spin-wait cannot deadlock.
__device__ __forceinline__ void gbar(int* bar, int phase){
  __syncthreads();
  if (threadIdx.x == 0){
    __threadfence();   // release: drain my block's global writes to coherence point
    __hip_atomic_fetch_add(&bar[phase], 1, __ATOMIC_ACQ_REL, __HIP_MEMORY_SCOPE_AGENT);
    while (__hip_atomic_load(&bar[phase], __ATOMIC_ACQUIRE, __HIP_MEMORY_SCOPE_AGENT) < 256)
      __builtin_amdgcn_s_sleep(2);
    __threadfence();   // acquire: invalidate caches before reading others' writes
  }
  __syncthreads();
}

__global__ __launch_bounds__(64) void init_barrier(int* bar){
  if (threadIdx.x < 16) bar[threadIdx.x] = 0;
}

#define GS 144

// ======== single persistent kernel: 8 phases, manual grid barrier between ========
__global__ __launch_bounds__(256, 2) void mega_kernel(
    const float* __restrict__ u, const float* __restrict__ W_in, const float* __restrict__ dt_bias,
    const float* __restrict__ B_bias, const float* __restrict__ C_bias,
    const float* __restrict__ Bn_w, const float* __restrict__ Cn_w,
    const float* __restrict__ D_par, const float* __restrict__ W_out, float* __restrict__ out,
    short* __restrict__ u16, short* __restrict__ WtIn, short* __restrict__ WtOut,
    float* __restrict__ proj, float* __restrict__ cosb, float* __restrict__ sinb,
    short* __restrict__ Bb, short* __restrict__ Cb, short* __restrict__ xTb,
    float* __restrict__ Lcum, float* __restrict__ u2b, float* __restrict__ c1b,
    short* __restrict__ Hpart, short* __restrict__ Hused, short* __restrict__ yb16,
    int* bar)
{
  __shared__ __align__(16) union SMem {
    float tile[32][132];                                                  // transpose
    struct { short As[2][4096]; short Bs[2][5120]; } g1;                  // gemm1 (36 KB)
    struct { short As[2][4096]; short Bs[2][4096]; } g2;                  // gemm2 (32 KB)
    float wsum[4];                                                        // scans
    struct { float vv[2][128]; float red[4]; } bc;                        // rmsnorm
    struct { short Bsm[16384]; float wS[128]; } hp;                       // hpart (33 KB)
    struct { short Gt[128 * GS]; float Lc[128], u2v[128], c1v[128]; } ck; // chunky (38.4 KB)
  } sm;
  const int tid = threadIdx.x;
  const int bid = blockIdx.x;

  // ---- Phase 0: prep — cast u | transpose W_in | transpose W_out | zero out (3680 units) ----
  #pragma unroll 1
  for (int it = 0; it < 15; ++it){
    int b = bid + 256 * it;
    if (b >= 3680) break;
    if (b < 1024){
      int i = (b * 256 + tid) * 4;
      f4 v = *(const f4*)(u + i);
      uint2 pk; pk.x = pack2(v.x, v.y); pk.y = pack2(v.z, v.w);
      *(uint2*)(u16 + i) = pk;
    } else if (b >= 2656){
      int i = ((b - 2656) * 256 + tid) * 4;
      *(f4*)(out + i) = (f4){0.f, 0.f, 0.f, 0.f};
    } else {
      const float* in; short* outp; int R, lda, bx, by;
      if (b < 2144){ int idx = b - 1024; bx = idx % 140; by = idx / 140; in = W_in;  outp = WtIn;  R = 1024; lda = 4480; }
      else         { int idx = b - 2144; bx = idx & 31;  by = idx >> 5;  in = W_out; outp = WtOut; R = 2048; lda = 1024; }
      int bc0 = bx * 32, br = by * 128;
      int c = tid & 31, r0 = tid >> 5;
      #pragma unroll
      for (int i = 0; i < 16; i++){
        int r = r0 + i * 8;
        sm.tile[c][r] = in[(size_t)(br + r) * lda + bc0 + c];
      }
      __syncthreads();
      #pragma unroll
      for (int i = 0; i < 4; i++){
        int task = tid + 256 * i;
        int cc = task >> 5;
        int rg = (task & 31) * 4;
        f4 v = *(const f4*)&sm.tile[cc][rg];
        uint2 pk; pk.x = pack2(v.x, v.y); pk.y = pack2(v.z, v.w);
        *(uint2*)(outp + (size_t)(bc0 + cc) * R + br + rg) = pk;
      }
      __syncthreads();
    }
  }
  gbar(bar, 0);

  // ---- Phase 1: GEMM1 proj = u16 @ WtInᵀ; 128x160 tile, 224 units ----
  if (bid < 224){
    const int N = 4480, K = 1024;
    const int wave = tid >> 6, lane = tid & 63;
    const int m0 = (bid / 28) * 128;
    const int n0 = (bid % 28) * 160;
    const int wm = (wave >> 1) * 64, wn = (wave & 1) * 80;
    const int quad = lane >> 4, r16 = lane & 15;
    f4 acc[4][5];
    #pragma unroll
    for (int i = 0; i < 4; i++)
      #pragma unroll
      for (int j = 0; j < 5; j++) acc[i][j] = (f4){0.f, 0.f, 0.f, 0.f};
    const int row0 = tid >> 2;
    const int kq   = tid & 3;
    const short* gA0 = u16  + (size_t)(m0 + row0) * K + kq * 8;
    const short* gA1 = u16  + (size_t)(m0 + row0 + 64) * K + kq * 8;
    const short* gB0 = WtIn + (size_t)(n0 + row0) * K + kq * 8;
    const short* gB1 = WtIn + (size_t)(n0 + row0 + 64) * K + kq * 8;
    const short* gB2 = WtIn + (size_t)(n0 + row0 + 128) * K + kq * 8;
    gload_lds16(gA0, &sm.g1.As[0][(size_t)tid * 8]);
    gload_lds16(gA1, &sm.g1.As[0][(size_t)(tid + 256) * 8]);
    gload_lds16(gB0, &sm.g1.Bs[0][(size_t)tid * 8]);
    gload_lds16(gB1, &sm.g1.Bs[0][(size_t)(tid + 256) * 8]);
    if (tid < 128) gload_lds16(gB2, &sm.g1.Bs[0][(size_t)(tid + 512) * 8]);
    for (int kt = 0; kt < 32; ++kt){
      const int cur = kt & 1;
      __syncthreads();
      if (kt + 1 < 32){
        const int ko = (kt + 1) * 32;
        const int nxt = cur ^ 1;
        gload_lds16(gA0 + ko, &sm.g1.As[nxt][(size_t)tid * 8]);
        gload_lds16(gA1 + ko, &sm.g1.As[nxt][(size_t)(tid + 256) * 8]);
        gload_lds16(gB0 + ko, &sm.g1.Bs[nxt][(size_t)tid * 8]);
        gload_lds16(gB1 + ko, &sm.g1.Bs[nxt][(size_t)(tid + 256) * 8]);
        if (tid < 128) gload_lds16(gB2 + ko, &sm.g1.Bs[nxt][(size_t)(tid + 512) * 8]);
      }
      short8 af[4], bf[5];
      #pragma unroll
      for (int i = 0; i < 4; i++)
        af[i] = *(const short8*)&sm.g1.As[cur][(wm + i * 16 + r16) * 32 + quad * 8];
      #pragma unroll
      for (int j = 0; j < 5; j++)
        bf[j] = *(const short8*)&sm.g1.Bs[cur][(wn + j * 16 + r16) * 32 + quad * 8];
      #pragma unroll
      for (int i = 0; i < 4; i++)
        #pragma unroll
        for (int j = 0; j < 5; j++)
          acc[i][j] = __builtin_amdgcn_mfma_f32_16x16x32_bf16(af[i], bf[j], acc[i][j], 0, 0, 0);
    }
    #pragma unroll
    for (int i = 0; i < 4; i++)
      #pragma unroll
      for (int j = 0; j < 5; j++)
        #pragma unroll
        for (int rr = 0; rr < 4; ++rr){
          int row = m0 + wm + i * 16 + quad * 4 + rr;
          int col = n0 + wn + j * 16 + r16;
          proj[(size_t)row * N + col] = acc[i][j][rr];
        }
  }
  gbar(bar, 1);

  // ---- Phase 2: per-head L-scan (32 units on bid<32) + theta cumsum (1024 units) ----
  {
    int lane = tid & 63, wave = tid >> 6;
    int t0 = tid * 4;
    if (bid < 32){
      int h = bid;
      float dtbias = dt_bias[h];
      float dt5[5], lam5[5];
      #pragma unroll
      for (int i = 0; i < 5; i++){
        int t = t0 + i;
        if (t < 1024){
          const float* row = proj + (size_t)t * DPROJ;
          dt5[i]  = softplus_f(row[4352 + h] + dtbias);
          lam5[i] = 1.f / (1.f + __expf(-row[4416 + h]));
        } else { dt5[i] = 0.f; lam5[i] = 0.f; }
      }
      float v[4], c1[4], c2n[4];
      #pragma unroll
      for (int i = 0; i < 4; i++){
        int t = t0 + i;
        const float* row = proj + (size_t)t * DPROJ;
        float Ah = -fmaxf(softplus_f(row[4384 + h]), 1e-4f);
        v[i]   = Ah * dt5[i];
        c1[i]  = dt5[i] * lam5[i];
        c2n[i] = dt5[i + 1] * (1.f - lam5[i + 1]);
      }
      v[1] += v[0]; v[2] += v[1]; v[3] += v[2];
      float tot = v[3], sc = tot;
      #pragma unroll
      for (int off = 1; off < 64; off <<= 1){
        float n = __shfl_up(sc, off, 64);
        if (lane >= off) sc += n;
      }
      if (lane == 63) sm.wsum[wave] = sc;
      __syncthreads();
      float base = sc - tot;
      for (int w = 0; w < wave; ++w) base += sm.wsum[w];
      #pragma unroll
      for (int i = 0; i < 4; i++){
        int t = t0 + i;
        Lcum[h * 1024 + t] = base + v[i];
        u2b[h * 1024 + t]  = c1[i] + c2n[i];
        c1b[h * 1024 + t]  = c1[i];
      }
      __syncthreads();
    }
    #pragma unroll 1
    for (int it = 0; it < 4; ++it){
      int ub = bid + 256 * it;          // 0..1023
      int h = ub >> 5, k = ub & 31;
      float dtbias = dt_bias[h];
      float v[4];
      #pragma unroll
      for (int i = 0; i < 4; i++){
        const float* row = proj + (size_t)(t0 + i) * DPROJ;
        float dt = softplus_f(row[4352 + h] + dtbias);
        v[i] = row[4448 + k] * dt;
      }
      v[1] += v[0]; v[2] += v[1]; v[3] += v[2];
      float tot = v[3], sc = tot;
      #pragma unroll
      for (int off = 1; off < 64; off <<= 1){
        float n = __shfl_up(sc, off, 64);
        if (lane >= off) sc += n;
      }
      if (lane == 63) sm.wsum[wave] = sc;
      __syncthreads();
      float base = sc - tot;
      for (int w = 0; w < wave; ++w) base += sm.wsum[w];
      #pragma unroll
      for (int i = 0; i < 4; i++){
        float th = base + v[i];
        float s, c;
        __sincosf(th, &s, &c);
        int t = t0 + i;
        cosb[(size_t)t * 1024 + h * 32 + k] = c;
        sinb[(size_t)t * 1024 + h * 32 + k] = s;
      }
      __syncthreads();
    }
  }
  gbar(bar, 2);

  // ---- Phase 3: rmsnorm+bias+rope -> Bb/Cb (1024 units) | transpose x -> xTb (512 units) ----
  #pragma unroll 1
  for (int it = 0; it < 6; ++it){
    int b = bid + 256 * it;             // 0..1535
    if (b >= 1024){
      int idx = b - 1024;
      int bx = idx & 63, by = idx >> 6;
      int bc0 = bx * 32, br = by * 128;
      int c = tid & 31, r0 = tid >> 5;
      #pragma unroll
      for (int i = 0; i < 16; i++){
        int r = r0 + i * 8;
        sm.tile[c][r] = proj[(size_t)(br + r) * 4480 + 2048 + bc0 + c];
      }
      __syncthreads();
      #pragma unroll
      for (int i = 0; i < 4; i++){
        int task = tid + 256 * i;
        int cc = task >> 5;
        int rg = (task & 31) * 4;
        f4 v = *(const f4*)&sm.tile[cc][rg];
        uint2 pk; pk.x = pack2(v.x, v.y); pk.y = pack2(v.z, v.w);
        *(uint2*)(xTb + (size_t)(bc0 + cc) * 1024 + br + rg) = pk;
      }
      __syncthreads();
    } else {
      int t = b;
      int n = tid & 127;
      int isC = tid >> 7;
      float val = proj[(size_t)t * DPROJ + 4096 + isC * 128 + n];
      float ss = val * val;
      #pragma unroll
      for (int off = 32; off >= 1; off >>= 1) ss += __shfl_down(ss, off);
      int wave = tid >> 6, lane = tid & 63;
      if (lane == 0) sm.bc.red[wave] = ss;
      __syncthreads();
      float rsv = isC ? rsqrtf((sm.bc.red[2] + sm.bc.red[3]) * (1.f / 128.f) + 1e-5f)
                      : rsqrtf((sm.bc.red[0] + sm.bc.red[1]) * (1.f / 128.f) + 1e-5f);
      sm.bc.vv[isC][n] = val * rsv * (isC ? Cn_w[n] : Bn_w[n]);
      __syncthreads();
      const float* cb = cosb + (size_t)t * 1024;
      const float* sb = sinb + (size_t)t * 1024;
      #pragma unroll
      for (int it2 = 0; it2 < 8; it2++){
        int task = tid + 256 * it2;
        int arr  = task >> 10;
        int rem  = task & 1023;
        int h    = rem >> 5;
        int n0   = (rem & 31) * 4;
        const float* bias = arr ? C_bias : B_bias;
        const float* base = sm.bc.vv[arr];
        f4 bv = *(const f4*)&base[n0];
        f4 bi = *(const f4*)&bias[h * 128 + n0];
        f4 o;
        if (n0 < 32){
          f4 bv2 = *(const f4*)&base[n0 + 32];
          f4 bi2 = *(const f4*)&bias[h * 128 + n0 + 32];
          f4 cv = *(const f4*)&cb[h * 32 + n0];
          f4 sv = *(const f4*)&sb[h * 32 + n0];
          #pragma unroll
          for (int q = 0; q < 4; q++) o[q] = (bv[q] + bi[q]) * cv[q] - (bv2[q] + bi2[q]) * sv[q];
        } else if (n0 < 64){
          int k0 = n0 - 32;
          f4 bv1 = *(const f4*)&base[k0];
          f4 bi1 = *(const f4*)&bias[h * 128 + k0];
          f4 cv = *(const f4*)&cb[h * 32 + k0];
          f4 sv = *(const f4*)&sb[h * 32 + k0];
          #pragma unroll
          for (int q = 0; q < 4; q++) o[q] = (bv1[q] + bi1[q]) * sv[q] + (bv[q] + bi[q]) * cv[q];
        } else {
          #pragma unroll
          for (int q = 0; q < 4; q++) o[q] = bv[q] + bi[q];
        }
        uint2 pk; pk.x = pack2(o.x, o.y); pk.y = pack2(o.z, o.w);
        short* outp = arr ? Cb : Bb;
        *(uint2*)(outp + (size_t)t * 4096 + h * 128 + n0) = pk;
      }
      __syncthreads();
    }
  }
  gbar(bar, 3);

  // ---- Phase 4: hpart (256 units) — B-tile in LDS, MFMA ----
  {
    int h = bid >> 3, c = bid & 7;
    int t0 = c * 128;
    if (tid < 128){
      float Lend = Lcum[h * 1024 + t0 + 127];
      sm.hp.wS[tid] = __expf(Lend - Lcum[h * 1024 + t0 + tid]) * u2b[h * 1024 + t0 + tid];
    }
    #pragma unroll
    for (int it = 0; it < 8; it++){
      int slot = tid + 256 * it;
      int row = slot >> 4, c16 = slot & 15;
      gload_lds16(Bb + (size_t)(t0 + row) * 4096 + h * 128 + c16 * 8, &sm.hp.Bsm[(size_t)slot * 8]);
    }
    __syncthreads();
    int wave = tid >> 6, lane = tid & 63, quad = lane >> 4, r16 = lane & 15;
    int n0 = wave * 32;
    f4 acc[4][2];
    #pragma unroll
    for (int i = 0; i < 4; i++)
      #pragma unroll
      for (int j = 0; j < 2; j++) acc[i][j] = (f4){0.f, 0.f, 0.f, 0.f};
    #pragma unroll
    for (int kk = 0; kk < 4; ++kk){
      int sb = kk * 32 + quad * 8;
      short8 af[4];
      #pragma unroll
      for (int i = 0; i < 4; i++){
        int p = i * 16 + r16;
        af[i] = *(const short8*)(xTb + (size_t)(h * 64 + p) * 1024 + t0 + sb);
      }
      float wv[8];
      #pragma unroll
      for (int jj = 0; jj < 8; jj++) wv[jj] = sm.hp.wS[sb + jj];
      short8 bfr[2];
      #pragma unroll
      for (int j = 0; j < 2; j++){
        int nn = n0 + j * 16 + r16;
        float e[8];
        #pragma unroll
        for (int jj = 0; jj < 8; jj++)
          e[jj] = b2f((uint16_t)sm.hp.Bsm[(size_t)(sb + jj) * 128 + nn]) * wv[jj];
        union { short8 s; uint32_t u[4]; } fr;
        #pragma unroll
        for (int q = 0; q < 4; q++) fr.u[q] = pack2(e[2 * q], e[2 * q + 1]);
        bfr[j] = fr.s;
      }
      #pragma unroll
      for (int i = 0; i < 4; i++)
        #pragma unroll
        for (int j = 0; j < 2; j++)
          acc[i][j] = __builtin_amdgcn_mfma_f32_16x16x32_bf16(af[i], bfr[j], acc[i][j], 0, 0, 0);
    }
    short* outp = Hpart + ((size_t)(h * 8 + c)) * 8192;
    #pragma unroll
    for (int i = 0; i < 4; i++)
      #pragma unroll
      for (int rr = 0; rr < 4; ++rr){
        int p = i * 16 + quad * 4 + rr;
        #pragma unroll
        for (int j = 0; j < 2; j++){
          int nn = n0 + j * 16 + r16;
          outp[p * 128 + nn] = f2b(acc[i][j][rr]);
        }
      }
  }
  gbar(bar, 4);

  // ---- Phase 5: hscan (1024 units of 256 lanes) ----
  #pragma unroll 1
  for (int it = 0; it < 4; ++it){
    int idx = (bid + 256 * it) * 256 + tid;
    int h = idx >> 13, rem = idx & 8191;
    float acc = 0.f;
    float Lprev = 0.f;
    #pragma unroll
    for (int c = 0; c < 8; c++){
      Hused[((size_t)(h * 8 + c)) * 8192 + rem] = f2b(acc);
      float Lend = Lcum[h * 1024 + c * 128 + 127];
      float dec = __expf(Lend - Lprev);
      acc = dec * acc + b2f((uint16_t)Hpart[((size_t)(h * 8 + c)) * 8192 + rem]);
      Lprev = Lend;
    }
  }
  gbar(bar, 5);

  // ---- Phase 6: chunky (256 units) + fused D/silu epilogue -> yb16 ----
  {
    int h = bid >> 3, c = bid & 7;
    int t0 = c * 128;
    if (tid < 128){
      sm.ck.Lc[tid]  = Lcum[h * 1024 + t0 + tid];
      sm.ck.u2v[tid] = u2b[h * 1024 + t0 + tid];
      sm.ck.c1v[tid] = c1b[h * 1024 + t0 + tid];
    }
    float Lprev = (c > 0) ? Lcum[h * 1024 + t0 - 1] : 0.f;
    float Dp = D_par[h];
    int wave = tid >> 6, lane = tid & 63, quad = lane >> 4, r16 = lane & 15;
    int wm = (wave >> 1) * 64, wn = (wave & 1) * 64;

    f4 acc[4][4];
    #pragma unroll
    for (int i = 0; i < 4; i++)
      #pragma unroll
      for (int j = 0; j < 4; j++) acc[i][j] = (f4){0.f, 0.f, 0.f, 0.f};
    #pragma unroll
    for (int kk = 0; kk < 4; ++kk){
      short8 af[4], bf[4];
      #pragma unroll
      for (int i = 0; i < 4; i++)
        af[i] = *(const short8*)(Cb + (size_t)(t0 + wm + i * 16 + r16) * 4096 + h * 128 + kk * 32 + quad * 8);
      #pragma unroll
      for (int j = 0; j < 4; j++)
        bf[j] = *(const short8*)(Bb + (size_t)(t0 + wn + j * 16 + r16) * 4096 + h * 128 + kk * 32 + quad * 8);
      #pragma unroll
      for (int i = 0; i < 4; i++)
        #pragma unroll
        for (int j = 0; j < 4; j++)
          acc[i][j] = __builtin_amdgcn_mfma_f32_16x16x32_bf16(af[i], bf[j], acc[i][j], 0, 0, 0);
    }
    __syncthreads();
    #pragma unroll
    for (int i = 0; i < 4; i++){
      #pragma unroll
      for (int rr = 0; rr < 4; ++rr){
        int trow = wm + i * 16 + quad * 4 + rr;
        float Lt = sm.ck.Lc[trow];
        #pragma unroll
        for (int j = 0; j < 4; j++){
          int scol = wn + j * 16 + r16;
          float g = 0.f;
          if (scol <= trow){
            float wcoef = (scol == trow) ? sm.ck.c1v[scol] : sm.ck.u2v[scol];
            g = acc[i][j][rr] * wcoef * __expf(Lt - sm.ck.Lc[scol]);
          }
          sm.ck.Gt[trow * GS + scol] = f2b(g);
        }
      }
    }
    __syncthreads();
    f4 accY[2][4], accZ[2][4];
    #pragma unroll
    for (int i = 0; i < 2; i++)
      #pragma unroll
      for (int j = 0; j < 4; j++){ accY[i][j] = (f4){0.f,0.f,0.f,0.f}; accZ[i][j] = (f4){0.f,0.f,0.f,0.f}; }
    int m0 = wave * 32;
    #pragma unroll
    for (int kk = 0; kk < 4; ++kk){
      short8 ag[2], ac[2], bx[4], bh[4];
      #pragma unroll
      for (int i = 0; i < 2; i++){
        ag[i] = *(const short8*)&sm.ck.Gt[(m0 + i * 16 + r16) * GS + kk * 32 + quad * 8];
        ac[i] = *(const short8*)(Cb + (size_t)(t0 + m0 + i * 16 + r16) * 4096 + h * 128 + kk * 32 + quad * 8);
      }
      #pragma unroll
      for (int j = 0; j < 4; j++){
        bx[j] = *(const short8*)(xTb + (size_t)(h * 64 + j * 16 + r16) * 1024 + t0 + kk * 32 + quad * 8);
        bh[j] = *(const short8*)(Hused + ((size_t)(h * 8 + c) * 64 + j * 16 + r16) * 128 + kk * 32 + quad * 8);
      }
      #pragma unroll
      for (int i = 0; i < 2; i++)
        #pragma unroll
        for (int j = 0; j < 4; j++){
          accY[i][j] = __builtin_amdgcn_mfma_f32_16x16x32_bf16(ag[i], bx[j], accY[i][j], 0, 0, 0);
          accZ[i][j] = __builtin_amdgcn_mfma_f32_16x16x32_bf16(ac[i], bh[j], accZ[i][j], 0, 0, 0);
        }
    }
    #pragma unroll
    for (int i = 0; i < 2; i++)
      #pragma unroll
      for (int rr = 0; rr < 4; ++rr){
        int trow = m0 + i * 16 + quad * 4 + rr;
        float ei = __expf(sm.ck.Lc[trow] - Lprev);
        const float* prow = proj + (size_t)(t0 + trow) * DPROJ;
        #pragma unroll
        for (int j = 0; j < 4; j++){
          int col = h * 64 + j * 16 + r16;
          float zv = prow[col];
          float xv = prow[2048 + col];
          float yv = accY[i][j][rr] + ei * accZ[i][j][rr] + Dp * xv;
          float o = yv * (zv / (1.f + __expf(-zv)));
          yb16[(size_t)(t0 + trow) * 2048 + col] = f2b(o);
        }
      }
  }
  gbar(bar, 6);

  // ---- Phase 7: GEMM2 out += yb16 @ WtOutᵀ, split-K=4 (256 units), fp32 atomics ----
  {
    const int N = 1024, K = 2048, klen = 512;
    const int wave = tid >> 6, lane = tid & 63;
    const int n0 = (bid & 7) * 128;
    const int m0 = ((bid >> 3) & 7) * 128;
    const int k0 = (bid >> 6) * klen;
    const int wm = (wave >> 1) * 64, wn = (wave & 1) * 64;
    const int quad = lane >> 4, r16 = lane & 15;
    f4 acc[4][4];
    #pragma unroll
    for (int i = 0; i < 4; i++)
      #pragma unroll
      for (int j = 0; j < 4; j++) acc[i][j] = (f4){0.f, 0.f, 0.f, 0.f};
    const int row0 = tid >> 2;
    const int kq   = tid & 3;
    const short* gA0 = yb16  + (size_t)(m0 + row0) * K + k0 + kq * 8;
    const short* gA1 = yb16  + (size_t)(m0 + row0 + 64) * K + k0 + kq * 8;
    const short* gB0 = WtOut + (size_t)(n0 + row0) * K + k0 + kq * 8;
    const short* gB1 = WtOut + (size_t)(n0 + row0 + 64) * K + k0 + kq * 8;
    gload_lds16(gA0, &sm.g2.As[0][(size_t)tid * 8]);
    gload_lds16(gA1, &sm.g2.As[0][(size_t)(tid + 256) * 8]);
    gload_lds16(gB0, &sm.g2.Bs[0][(size_t)tid * 8]);
    gload_lds16(gB1, &sm.g2.Bs[0][(size_t)(tid + 256) * 8]);
    for (int kt = 0; kt < klen / 32; ++kt){
      const int cur = kt & 1;
      __syncthreads();
      if (kt + 1 < klen / 32){
        const int ko = (kt + 1) * 32;
        const int nxt = cur ^ 1;
        gload_lds16(gA0 + ko, &sm.g2.As[nxt][(size_t)tid * 8]);
        gload_lds16(gA1 + ko, &sm.g2.As[nxt][(size_t)(tid + 256) * 8]);
        gload_lds16(gB0 + ko, &sm.g2.Bs[nxt][(size_t)tid * 8]);
        gload_lds16(gB1 + ko, &sm.g2.Bs[nxt][(size_t)(tid + 256) * 8]);
      }
      short8 af[4], bf[4];
      #pragma unroll
      for (int i = 0; i < 4; i++){
        af[i] = *(const short8*)&sm.g2.As[cur][(wm + i * 16 + r16) * 32 + quad * 8];
        bf[i] = *(const short8*)&sm.g2.Bs[cur][(wn + i * 16 + r16) * 32 + quad * 8];
      }
      #pragma unroll
      for (int i = 0; i < 4; i++)
        #pragma unroll
        for (int j = 0; j < 4; j++)
          acc[i][j] = __builtin_amdgcn_mfma_f32_16x16x32_bf16(af[i], bf[j], acc[i][j], 0, 0, 0);
    }
    #pragma unroll
    for (int i = 0; i < 4; i++)
      #pragma unroll
      for (int j = 0; j < 4; j++)
        #pragma unroll
        for (int rr = 0; rr < 4; ++rr){
          int row = m0 + wm + i * 16 + quad * 4 + rr;
          int col = n0 + wn + j * 16 + r16;
          unsafeAtomicAdd(&out[(size_t)row * N + col], acc[i][j][rr]);
        }
  }
}

extern "C" void kernel_launch(void* const* d_in, const int* in_sizes, int n_in,
                              void* d_out, int out_size, void* d_ws, size_t ws_size,
                              hipStream_t stream){
  const float* u       = (const float*)d_in[0];
  const float* W_in    = (const float*)d_in[1];
  const float* dt_bias = (const float*)d_in[2];
  const float* B_bias  = (const float*)d_in[3];
  const float* C_bias  = (const float*)d_in[4];
  const float* Bn_w    = (const float*)d_in[5];
  const float* Cn_w    = (const float*)d_in[6];
  const float* D_par   = (const float*)d_in[7];
  const float* W_out   = (const float*)d_in[8];
  float* out = (float*)d_out;

  char* ws = (char*)d_ws;
  short* u16   = (short*)(ws + 0);
  short* WtIn  = (short*)(ws + 2097152);
  short* WtOut = (short*)(ws + 11272192);
  float* proj  = (float*)(ws + 15466496);
  float* cosb  = (float*)(ws + 33816576);
  float* sinb  = (float*)(ws + 38010880);
  short* Bb    = (short*)(ws + 42205184);
  short* Cb    = (short*)(ws + 50593792);
  short* xTb   = (short*)(ws + 58982400);
  float* Lcum  = (float*)(ws + 63176704);
  float* u2b   = (float*)(ws + 63307776);
  float* c1b   = (float*)(ws + 63438848);
  short* Hpart = (short*)(ws + 63569920);
  short* Hused = (short*)(ws + 67764224);
  short* yb16  = (short*)(ws + 71958528);
  int*   bar   = (int*)  (ws + 76152832);   // 64 B of barrier counters -> total 76,152,896 B

  init_barrier<<<1, 64, 0, stream>>>(bar);
  mega_kernel<<<256, 256, 0, stream>>>(u, W_in, dt_bias, B_bias, C_bias, Bn_w, Cn_w, D_par,
                                       W_out, out, u16, WtIn, WtOut, proj, cosb, sinb,
                                       Bb, Cb, xTb, Lcum, u2b, c1b, Hpart, Hused, yb16, bar);
}

// Round 12
// 203.000 us; speedup vs baseline: 2.4164x; 2.4164x over previous
//
#include <hip/hip_runtime.h>
#include <stdint.h>

#define SEQ     1024
#define DPROJ   4480
// proj columns: z=0, x=2048, Bp=4096, Cp=4224, dd_dt=4352, dd_A=4384, trap=4416, ang=4448

typedef __attribute__((ext_vector_type(8))) short short8;
typedef __attribute__((ext_vector_type(4))) float f4;

__device__ __forceinline__ short f2b(float f){
  union { float f; uint32_t u; } v; v.f = f;
  uint32_t r = (v.u + 0x7fffu + ((v.u >> 16) & 1u)) >> 16;
  return (short)(uint16_t)r;
}
__device__ __forceinline__ float b2f(uint16_t u){
  union { uint32_t u; float f; } v; v.u = ((uint32_t)u) << 16; return v.f;
}
__device__ __forceinline__ uint32_t pack2(float lo, float hi){
  return (uint32_t)(uint16_t)f2b(lo) | ((uint32_t)(uint16_t)f2b(hi) << 16);
}
__device__ __forceinline__ float softplus_f(float x){
  return x > 20.f ? x : log1pf(__expf(x));
}
// async global->LDS 16B/lane; lds dest must be wave-uniform base + lane*16 order
__device__ __forceinline__ void gload_lds16(const short* g, short* l){
  __builtin_amdgcn_global_load_lds((const __attribute__((address_space(1))) void*)g,
                                   (__attribute__((address_space(3))) void*)l, 16, 0, 0);
}

// ---- fused preprocessing: cast u | transpose W_in | transpose W_out | zero out ----
// grid: [0,1024) cast, [1024,2144) W_in 140x8, [2144,2656) W_out 32x16, [2656,3680) zero
__global__ __launch_bounds__(256) void prep_inputs(const float* __restrict__ u, short* __restrict__ u16,
                                                   const float* __restrict__ W_in, short* __restrict__ WtIn,
                                                   const float* __restrict__ W_out, short* __restrict__ WtOut,
                                                   float* __restrict__ outz){
  int b = blockIdx.x;
  int tid = threadIdx.x;
  if (b < 1024){
    int i = (b * 256 + tid) * 4;
    f4 v = *(const f4*)(u + i);
    uint2 pk; pk.x = pack2(v.x, v.y); pk.y = pack2(v.z, v.w);
    *(uint2*)(u16 + i) = pk;
    return;
  }
  if (b >= 2656){
    int i = ((b - 2656) * 256 + tid) * 4;
    *(f4*)(outz + i) = (f4){0.f, 0.f, 0.f, 0.f};
    return;
  }
  const float* in; short* outp; int R, lda, bx, by;
  if (b < 2144){ int idx = b - 1024; bx = idx % 140; by = idx / 140; in = W_in;  outp = WtIn;  R = 1024; lda = 4480; }
  else         { int idx = b - 2144; bx = idx & 31;  by = idx >> 5;  in = W_out; outp = WtOut; R = 2048; lda = 1024; }
  __shared__ float tile[32][132];
  int bc = bx * 32, br = by * 128;
  int c = tid & 31, r0 = tid >> 5;
  #pragma unroll
  for (int i = 0; i < 16; i++){
    int r = r0 + i * 8;
    tile[c][r] = in[(size_t)(br + r) * lda + bc + c];
  }
  __syncthreads();
  #pragma unroll
  for (int i = 0; i < 4; i++){
    int task = tid + 256 * i;
    int cc = task >> 5;
    int rg = (task & 31) * 4;
    f4 v = *(const f4*)&tile[cc][rg];
    uint2 pk; pk.x = pack2(v.x, v.y); pk.y = pack2(v.z, v.w);
    *(uint2*)(outp + (size_t)(bc + cc) * R + br + rg) = pk;
  }
}

// ---- GEMM1: proj[1024][4480] = u16 @ WtInᵀ; 128x160 tile, 224 blocks, LDS double-buffer ----
__global__ __launch_bounds__(256) void gemm1_kernel(const short* __restrict__ A, const short* __restrict__ Bt,
                                                    float* __restrict__ C){
  const int N = 4480, K = 1024;
  __shared__ __align__(16) short As[2][128 * 32];
  __shared__ __align__(16) short Bs[2][160 * 32];
  const int tid  = threadIdx.x;
  const int wave = tid >> 6;
  const int lane = tid & 63;
  const int m0 = blockIdx.y * 128;
  const int n0 = blockIdx.x * 160;
  const int wm = (wave >> 1) * 64;
  const int wn = (wave & 1) * 80;
  const int quad = lane >> 4;
  const int r16  = lane & 15;

  f4 acc[4][5];
  #pragma unroll
  for (int i = 0; i < 4; i++)
    #pragma unroll
    for (int j = 0; j < 5; j++) acc[i][j] = (f4){0.f, 0.f, 0.f, 0.f};

  const int row0 = tid >> 2;
  const int kq   = tid & 3;
  const short* gA0 = A  + (size_t)(m0 + row0) * K + kq * 8;
  const short* gA1 = A  + (size_t)(m0 + row0 + 64) * K + kq * 8;
  const short* gB0 = Bt + (size_t)(n0 + row0) * K + kq * 8;
  const short* gB1 = Bt + (size_t)(n0 + row0 + 64) * K + kq * 8;
  const short* gB2 = Bt + (size_t)(n0 + row0 + 128) * K + kq * 8;   // tid<128 only

  gload_lds16(gA0, &As[0][(size_t)tid * 8]);
  gload_lds16(gA1, &As[0][(size_t)(tid + 256) * 8]);
  gload_lds16(gB0, &Bs[0][(size_t)tid * 8]);
  gload_lds16(gB1, &Bs[0][(size_t)(tid + 256) * 8]);
  if (tid < 128) gload_lds16(gB2, &Bs[0][(size_t)(tid + 512) * 8]);

  for (int kt = 0; kt < 32; ++kt){
    const int cur = kt & 1;
    __syncthreads();
    if (kt + 1 < 32){
      const int ko = (kt + 1) * 32;
      const int nxt = cur ^ 1;
      gload_lds16(gA0 + ko, &As[nxt][(size_t)tid * 8]);
      gload_lds16(gA1 + ko, &As[nxt][(size_t)(tid + 256) * 8]);
      gload_lds16(gB0 + ko, &Bs[nxt][(size_t)tid * 8]);
      gload_lds16(gB1 + ko, &Bs[nxt][(size_t)(tid + 256) * 8]);
      if (tid < 128) gload_lds16(gB2 + ko, &Bs[nxt][(size_t)(tid + 512) * 8]);
    }
    short8 af[4], bf[5];
    #pragma unroll
    for (int i = 0; i < 4; i++)
      af[i] = *(const short8*)&As[cur][(wm + i * 16 + r16) * 32 + quad * 8];
    #pragma unroll
    for (int j = 0; j < 5; j++)
      bf[j] = *(const short8*)&Bs[cur][(wn + j * 16 + r16) * 32 + quad * 8];
    #pragma unroll
    for (int i = 0; i < 4; i++)
      #pragma unroll
      for (int j = 0; j < 5; j++)
        acc[i][j] = __builtin_amdgcn_mfma_f32_16x16x32_bf16(af[i], bf[j], acc[i][j], 0, 0, 0);
  }

  #pragma unroll
  for (int i = 0; i < 4; i++)
    #pragma unroll
    for (int j = 0; j < 5; j++)
      #pragma unroll
      for (int rr = 0; rr < 4; ++rr){
        int row = m0 + wm + i * 16 + quad * 4 + rr;
        int col = n0 + wn + j * 16 + r16;
        C[(size_t)row * N + col] = acc[i][j][rr];
      }
}

// ---- GEMM2: out += yb16 @ WtOutᵀ, split-K=4, fp32 atomics, LDS double-buffer ----
__global__ __launch_bounds__(256) void gemm2_kernel(const short* __restrict__ A, const short* __restrict__ Bt,
                                                    float* __restrict__ C){
  const int N = 1024, K = 2048, klen = 512;
  __shared__ __align__(16) short As[2][128 * 32];
  __shared__ __align__(16) short Bs[2][128 * 32];
  const int tid  = threadIdx.x;
  const int wave = tid >> 6;
  const int lane = tid & 63;
  const int m0 = blockIdx.y * 128;
  const int n0 = blockIdx.x * 128;
  const int k0 = blockIdx.z * klen;
  const int wm = (wave >> 1) * 64;
  const int wn = (wave & 1) * 64;
  const int quad = lane >> 4;
  const int r16  = lane & 15;

  f4 acc[4][4];
  #pragma unroll
  for (int i = 0; i < 4; i++)
    #pragma unroll
    for (int j = 0; j < 4; j++) acc[i][j] = (f4){0.f, 0.f, 0.f, 0.f};

  const int row0 = tid >> 2;
  const int kq   = tid & 3;
  const short* gA0 = A  + (size_t)(m0 + row0) * K + k0 + kq * 8;
  const short* gA1 = A  + (size_t)(m0 + row0 + 64) * K + k0 + kq * 8;
  const short* gB0 = Bt + (size_t)(n0 + row0) * K + k0 + kq * 8;
  const short* gB1 = Bt + (size_t)(n0 + row0 + 64) * K + k0 + kq * 8;

  gload_lds16(gA0, &As[0][(size_t)tid * 8]);
  gload_lds16(gA1, &As[0][(size_t)(tid + 256) * 8]);
  gload_lds16(gB0, &Bs[0][(size_t)tid * 8]);
  gload_lds16(gB1, &Bs[0][(size_t)(tid + 256) * 8]);

  for (int kt = 0; kt < klen / 32; ++kt){
    const int cur = kt & 1;
    __syncthreads();
    if (kt + 1 < klen / 32){
      const int ko = (kt + 1) * 32;
      const int nxt = cur ^ 1;
      gload_lds16(gA0 + ko, &As[nxt][(size_t)tid * 8]);
      gload_lds16(gA1 + ko, &As[nxt][(size_t)(tid + 256) * 8]);
      gload_lds16(gB0 + ko, &Bs[nxt][(size_t)tid * 8]);
      gload_lds16(gB1 + ko, &Bs[nxt][(size_t)(tid + 256) * 8]);
    }
    short8 af[4], bf[4];
    #pragma unroll
    for (int i = 0; i < 4; i++){
      af[i] = *(const short8*)&As[cur][(wm + i * 16 + r16) * 32 + quad * 8];
      bf[i] = *(const short8*)&Bs[cur][(wn + i * 16 + r16) * 32 + quad * 8];
    }
    #pragma unroll
    for (int i = 0; i < 4; i++)
      #pragma unroll
      for (int j = 0; j < 4; j++)
        acc[i][j] = __builtin_amdgcn_mfma_f32_16x16x32_bf16(af[i], bf[j], acc[i][j], 0, 0, 0);
  }

  #pragma unroll
  for (int i = 0; i < 4; i++)
    #pragma unroll
    for (int j = 0; j < 4; j++)
      #pragma unroll
      for (int rr = 0; rr < 4; ++rr){
        int row = m0 + wm + i * 16 + quad * 4 + rr;
        int col = n0 + wn + j * 16 + r16;
        unsafeAtomicAdd(&C[(size_t)row * N + col], acc[i][j][rr]);
      }
}

// ---- fused: [0,32) per-head prefix scan (Lcum/u2b/c1b) | [32,1056) theta cumsum+sincos ----
__global__ __launch_bounds__(256) void scan_theta(const float* __restrict__ proj,
                                                  const float* __restrict__ dt_bias,
                                                  float* __restrict__ Lcum, float* __restrict__ u2b,
                                                  float* __restrict__ c1b,
                                                  float* __restrict__ cosb, float* __restrict__ sinb){
  int b = blockIdx.x;
  int tid = threadIdx.x;
  int t0 = tid * 4;
  int lane = tid & 63, wave = tid >> 6;
  __shared__ float wsum[4];
  if (b < 32){
    int h = b;
    float dtbias = dt_bias[h];
    float dt5[5], lam5[5];
    #pragma unroll
    for (int i = 0; i < 5; i++){
      int t = t0 + i;
      if (t < 1024){
        const float* row = proj + (size_t)t * DPROJ;
        dt5[i]  = softplus_f(row[4352 + h] + dtbias);
        lam5[i] = 1.f / (1.f + __expf(-row[4416 + h]));
      } else { dt5[i] = 0.f; lam5[i] = 0.f; }
    }
    float v[4], c1[4], c2n[4];
    #pragma unroll
    for (int i = 0; i < 4; i++){
      int t = t0 + i;
      const float* row = proj + (size_t)t * DPROJ;
      float Ah = -fmaxf(softplus_f(row[4384 + h]), 1e-4f);
      v[i]   = Ah * dt5[i];
      c1[i]  = dt5[i] * lam5[i];
      c2n[i] = dt5[i + 1] * (1.f - lam5[i + 1]);
    }
    v[1] += v[0]; v[2] += v[1]; v[3] += v[2];
    float tot = v[3], sc = tot;
    #pragma unroll
    for (int off = 1; off < 64; off <<= 1){
      float n = __shfl_up(sc, off, 64);
      if (lane >= off) sc += n;
    }
    if (lane == 63) wsum[wave] = sc;
    __syncthreads();
    float base = sc - tot;
    for (int w = 0; w < wave; ++w) base += wsum[w];
    #pragma unroll
    for (int i = 0; i < 4; i++){
      int t = t0 + i;
      Lcum[h * 1024 + t] = base + v[i];
      u2b[h * 1024 + t]  = c1[i] + c2n[i];
      c1b[h * 1024 + t]  = c1[i];
    }
  } else {
    int hk = b - 32;
    int h = hk >> 5, k = hk & 31;
    float dtbias = dt_bias[h];
    float v[4];
    #pragma unroll
    for (int i = 0; i < 4; i++){
      const float* row = proj + (size_t)(t0 + i) * DPROJ;
      float dt = softplus_f(row[4352 + h] + dtbias);
      v[i] = row[4448 + k] * dt;
    }
    v[1] += v[0]; v[2] += v[1]; v[3] += v[2];
    float tot = v[3], sc = tot;
    #pragma unroll
    for (int off = 1; off < 64; off <<= 1){
      float n = __shfl_up(sc, off, 64);
      if (lane >= off) sc += n;
    }
    if (lane == 63) wsum[wave] = sc;
    __syncthreads();
    float base = sc - tot;
    for (int w = 0; w < wave; ++w) base += wsum[w];
    #pragma unroll
    for (int i = 0; i < 4; i++){
      float th = base + v[i];
      float s, c;
      __sincosf(th, &s, &c);
      int t = t0 + i;
      cosb[(size_t)t * 1024 + h * 32 + k] = c;
      sinb[(size_t)t * 1024 + h * 32 + k] = s;
    }
  }
}

// ---- fused: [0,1024) rmsnorm+bias+rope -> Bb/Cb | [1024,1536) transpose x -> xTb ----
__global__ __launch_bounds__(256) void bcxt_kernel(const float* __restrict__ proj,
                                                   const float* __restrict__ B_bias, const float* __restrict__ C_bias,
                                                   const float* __restrict__ Bn_w, const float* __restrict__ Cn_w,
                                                   const float* __restrict__ cosb, const float* __restrict__ sinb,
                                                   short* __restrict__ Bb, short* __restrict__ Cb,
                                                   short* __restrict__ xTb){
  int b = blockIdx.x;
  int tid = threadIdx.x;
  if (b >= 1024){
    int idx = b - 1024;             // transpose x: grid 64x8, R=1024, lda=4480, c0=2048
    int bx = idx & 63, by = idx >> 6;
    __shared__ float tile[32][132];
    int bc = bx * 32, br = by * 128;
    int c = tid & 31, r0 = tid >> 5;
    #pragma unroll
    for (int i = 0; i < 16; i++){
      int r = r0 + i * 8;
      tile[c][r] = proj[(size_t)(br + r) * 4480 + 2048 + bc + c];
    }
    __syncthreads();
    #pragma unroll
    for (int i = 0; i < 4; i++){
      int task = tid + 256 * i;
      int cc = task >> 5;
      int rg = (task & 31) * 4;
      f4 v = *(const f4*)&tile[cc][rg];
      uint2 pk; pk.x = pack2(v.x, v.y); pk.y = pack2(v.z, v.w);
      *(uint2*)(xTb + (size_t)(bc + cc) * 1024 + br + rg) = pk;
    }
    return;
  }
  int t = b;
  __shared__ float vv[2][128];
  __shared__ float red[4];
  int n = tid & 127;
  int isC = tid >> 7;
  float val = proj[(size_t)t * DPROJ + 4096 + isC * 128 + n];
  float ss = val * val;
  #pragma unroll
  for (int off = 32; off >= 1; off >>= 1) ss += __shfl_down(ss, off);
  int wave = tid >> 6, lane = tid & 63;
  if (lane == 0) red[wave] = ss;
  __syncthreads();
  float rsv = isC ? rsqrtf((red[2] + red[3]) * (1.f / 128.f) + 1e-5f)
                  : rsqrtf((red[0] + red[1]) * (1.f / 128.f) + 1e-5f);
  vv[isC][n] = val * rsv * (isC ? Cn_w[n] : Bn_w[n]);
  __syncthreads();
  const float* cb = cosb + (size_t)t * 1024;
  const float* sb = sinb + (size_t)t * 1024;
  #pragma unroll
  for (int it = 0; it < 8; it++){
    int task = tid + 256 * it;
    int arr  = task >> 10;
    int rem  = task & 1023;
    int h    = rem >> 5;
    int n0   = (rem & 31) * 4;
    const float* bias = arr ? C_bias : B_bias;
    const float* base = vv[arr];
    f4 bv = *(const f4*)&base[n0];
    f4 bi = *(const f4*)&bias[h * 128 + n0];
    f4 o;
    if (n0 < 32){
      f4 bv2 = *(const f4*)&base[n0 + 32];
      f4 bi2 = *(const f4*)&bias[h * 128 + n0 + 32];
      f4 cv = *(const f4*)&cb[h * 32 + n0];
      f4 sv = *(const f4*)&sb[h * 32 + n0];
      #pragma unroll
      for (int q = 0; q < 4; q++) o[q] = (bv[q] + bi[q]) * cv[q] - (bv2[q] + bi2[q]) * sv[q];
    } else if (n0 < 64){
      int k0 = n0 - 32;
      f4 bv1 = *(const f4*)&base[k0];
      f4 bi1 = *(const f4*)&bias[h * 128 + k0];
      f4 cv = *(const f4*)&cb[h * 32 + k0];
      f4 sv = *(const f4*)&sb[h * 32 + k0];
      #pragma unroll
      for (int q = 0; q < 4; q++) o[q] = (bv1[q] + bi1[q]) * sv[q] + (bv[q] + bi[q]) * cv[q];
    } else {
      #pragma unroll
      for (int q = 0; q < 4; q++) o[q] = bv[q] + bi[q];
    }
    uint2 pk; pk.x = pack2(o.x, o.y); pk.y = pack2(o.z, o.w);
    short* outp = arr ? Cb : Bb;
    *(uint2*)(outp + (size_t)t * 4096 + h * 128 + n0) = pk;
  }
}

// ---- per-chunk state contribution, MFMA form (verified R3; direct global gather) ----
__global__ __launch_bounds__(256) void hpart_kernel(const short* __restrict__ xTb, const short* __restrict__ Bb,
                                                    const float* __restrict__ Lcum, const float* __restrict__ u2b,
                                                    short* __restrict__ Hpart){
  int h = blockIdx.x >> 3, c = blockIdx.x & 7;
  int t0 = c * 128;
  int tid = threadIdx.x;
  __shared__ float wS[128];
  if (tid < 128){
    float Lend = Lcum[h * 1024 + t0 + 127];
    wS[tid] = __expf(Lend - Lcum[h * 1024 + t0 + tid]) * u2b[h * 1024 + t0 + tid];
  }
  __syncthreads();
  int wave = tid >> 6, lane = tid & 63, quad = lane >> 4, r16 = lane & 15;
  int n0 = wave * 32;
  f4 acc[4][2];
  #pragma unroll
  for (int i = 0; i < 4; i++)
    #pragma unroll
    for (int j = 0; j < 2; j++) acc[i][j] = (f4){0.f, 0.f, 0.f, 0.f};

  const ushort* Bh = (const ushort*)Bb + (size_t)t0 * 4096 + h * 128;
  #pragma unroll
  for (int kk = 0; kk < 4; ++kk){
    int sb = kk * 32 + quad * 8;
    short8 af[4];
    #pragma unroll
    for (int i = 0; i < 4; i++){
      int p = i * 16 + r16;
      af[i] = *(const short8*)(xTb + (size_t)(h * 64 + p) * 1024 + t0 + sb);
    }
    float wv[8];
    #pragma unroll
    for (int jj = 0; jj < 8; jj++) wv[jj] = wS[sb + jj];
    short8 bfr[2];
    #pragma unroll
    for (int j = 0; j < 2; j++){
      int nn = n0 + j * 16 + r16;
      float e[8];
      #pragma unroll
      for (int jj = 0; jj < 8; jj++)
        e[jj] = b2f(Bh[(size_t)(sb + jj) * 4096 + nn]) * wv[jj];
      union { short8 s; uint32_t u[4]; } fr;
      #pragma unroll
      for (int q = 0; q < 4; q++) fr.u[q] = pack2(e[2 * q], e[2 * q + 1]);
      bfr[j] = fr.s;
    }
    #pragma unroll
    for (int i = 0; i < 4; i++)
      #pragma unroll
      for (int j = 0; j < 2; j++)
        acc[i][j] = __builtin_amdgcn_mfma_f32_16x16x32_bf16(af[i], bfr[j], acc[i][j], 0, 0, 0);
  }

  short* out = Hpart + ((size_t)(h * 8 + c)) * 8192;
  #pragma unroll
  for (int i = 0; i < 4; i++)
    #pragma unroll
    for (int rr = 0; rr < 4; ++rr){
      int p = i * 16 + quad * 4 + rr;
      #pragma unroll
      for (int j = 0; j < 2; j++){
        int nn = n0 + j * 16 + r16;
        out[p * 128 + nn] = f2b(acc[i][j][rr]);
      }
    }
}

// ---- 8-step state prefix: Hused[h][c] = H̃_{c-1} (bf16) ----
__global__ __launch_bounds__(256) void hscan_kernel(const short* __restrict__ Hpart,
                                                    const float* __restrict__ Lcum,
                                                    short* __restrict__ Hused){
  int idx = blockIdx.x * 256 + threadIdx.x;
  int h = idx >> 13, rem = idx & 8191;
  float acc = 0.f;
  float Lprev = 0.f;
  #pragma unroll
  for (int c = 0; c < 8; c++){
    Hused[((size_t)(h * 8 + c)) * 8192 + rem] = f2b(acc);
    float Lend = Lcum[h * 1024 + c * 128 + 127];
    float dec = __expf(Lend - Lprev);
    acc = dec * acc + b2f((uint16_t)Hpart[((size_t)(h * 8 + c)) * 8192 + rem]);
    Lprev = Lend;
  }
}

// ---- chunked dual (R5 structure): per (h,c): S=C@Bᵀ -> weight -> Y = G@X + ei·(C@H̃ᵀ);
//      fused D/silu epilogue -> yb16 ----
#define GS 144
__global__ __launch_bounds__(256) void chunky_kernel(const short* __restrict__ Cb, const short* __restrict__ Bbg,
                                                     const short* __restrict__ xTb, const short* __restrict__ Hused,
                                                     const float* __restrict__ Lcum, const float* __restrict__ u2b,
                                                     const float* __restrict__ c1b,
                                                     const float* __restrict__ proj, const float* __restrict__ D_par,
                                                     short* __restrict__ yb16){
  int h = blockIdx.x >> 3, c = blockIdx.x & 7;
  int t0 = c * 128;
  __shared__ __align__(16) short Gt[128 * GS];
  __shared__ float Lc[128], u2v[128], c1v[128];
  int tid = threadIdx.x;
  if (tid < 128){
    Lc[tid]  = Lcum[h * 1024 + t0 + tid];
    u2v[tid] = u2b[h * 1024 + t0 + tid];
    c1v[tid] = c1b[h * 1024 + t0 + tid];
  }
  float Lprev = (c > 0) ? Lcum[h * 1024 + t0 - 1] : 0.f;
  float Dp = D_par[h];
  int wave = tid >> 6, lane = tid & 63, quad = lane >> 4, r16 = lane & 15;
  int wm = (wave >> 1) * 64, wn = (wave & 1) * 64;

  f4 acc[4][4];
  #pragma unroll
  for (int i = 0; i < 4; i++)
    #pragma unroll
    for (int j = 0; j < 4; j++) acc[i][j] = (f4){0.f, 0.f, 0.f, 0.f};
  #pragma unroll
  for (int kk = 0; kk < 4; ++kk){
    short8 af[4], bf[4];
    #pragma unroll
    for (int i = 0; i < 4; i++)
      af[i] = *(const short8*)(Cb + (size_t)(t0 + wm + i * 16 + r16) * 4096 + h * 128 + kk * 32 + quad * 8);
    #pragma unroll
    for (int j = 0; j < 4; j++)
      bf[j] = *(const short8*)(Bbg + (size_t)(t0 + wn + j * 16 + r16) * 4096 + h * 128 + kk * 32 + quad * 8);
    #pragma unroll
    for (int i = 0; i < 4; i++)
      #pragma unroll
      for (int j = 0; j < 4; j++)
        acc[i][j] = __builtin_amdgcn_mfma_f32_16x16x32_bf16(af[i], bf[j], acc[i][j], 0, 0, 0);
  }
  __syncthreads();

  #pragma unroll
  for (int i = 0; i < 4; i++){
    #pragma unroll
    for (int rr = 0; rr < 4; ++rr){
      int trow = wm + i * 16 + quad * 4 + rr;
      float Lt = Lc[trow];
      #pragma unroll
      for (int j = 0; j < 4; j++){
        int scol = wn + j * 16 + r16;
        float g = 0.f;
        if (scol <= trow){
          float wcoef = (scol == trow) ? c1v[scol] : u2v[scol];
          g = acc[i][j][rr] * wcoef * __expf(Lt - Lc[scol]);
        }
        Gt[trow * GS + scol] = f2b(g);
      }
    }
  }
  __syncthreads();

  f4 accY[2][4], accZ[2][4];
  #pragma unroll
  for (int i = 0; i < 2; i++)
    #pragma unroll
    for (int j = 0; j < 4; j++){ accY[i][j] = (f4){0.f,0.f,0.f,0.f}; accZ[i][j] = (f4){0.f,0.f,0.f,0.f}; }
  int m0 = wave * 32;
  #pragma unroll
  for (int kk = 0; kk < 4; ++kk){
    short8 ag[2], ac[2], bx[4], bh[4];
    #pragma unroll
    for (int i = 0; i < 2; i++){
      ag[i] = *(const short8*)&Gt[(m0 + i * 16 + r16) * GS + kk * 32 + quad * 8];
      ac[i] = *(const short8*)(Cb + (size_t)(t0 + m0 + i * 16 + r16) * 4096 + h * 128 + kk * 32 + quad * 8);
    }
    #pragma unroll
    for (int j = 0; j < 4; j++){
      bx[j] = *(const short8*)(xTb + (size_t)(h * 64 + j * 16 + r16) * 1024 + t0 + kk * 32 + quad * 8);
      bh[j] = *(const short8*)(Hused + ((size_t)(h * 8 + c) * 64 + j * 16 + r16) * 128 + kk * 32 + quad * 8);
    }
    #pragma unroll
    for (int i = 0; i < 2; i++)
      #pragma unroll
      for (int j = 0; j < 4; j++){
        accY[i][j] = __builtin_amdgcn_mfma_f32_16x16x32_bf16(ag[i], bx[j], accY[i][j], 0, 0, 0);
        accZ[i][j] = __builtin_amdgcn_mfma_f32_16x16x32_bf16(ac[i], bh[j], accZ[i][j], 0, 0, 0);
      }
  }
  // fused post: y = (y + D*x) * silu(z), cast bf16
  #pragma unroll
  for (int i = 0; i < 2; i++)
    #pragma unroll
    for (int rr = 0; rr < 4; ++rr){
      int trow = m0 + i * 16 + quad * 4 + rr;
      float ei = __expf(Lc[trow] - Lprev);
      const float* prow = proj + (size_t)(t0 + trow) * DPROJ;
      #pragma unroll
      for (int j = 0; j < 4; j++){
        int col = h * 64 + j * 16 + r16;
        float zv = prow[col];
        float xv = prow[2048 + col];
        float yv = accY[i][j][rr] + ei * accZ[i][j][rr] + Dp * xv;
        float o = yv * (zv / (1.f + __expf(-zv)));
        yb16[(size_t)(t0 + trow) * 2048 + col] = f2b(o);
      }
    }
}

extern "C" void kernel_launch(void* const* d_in, const int* in_sizes, int n_in,
                              void* d_out, int out_size, void* d_ws, size_t ws_size,
                              hipStream_t stream){
  const float* u       = (const float*)d_in[0];
  const float* W_in    = (const float*)d_in[1];
  const float* dt_bias = (const float*)d_in[2];
  const float* B_bias  = (const float*)d_in[3];
  const float* C_bias  = (const float*)d_in[4];
  const float* Bn_w    = (const float*)d_in[5];
  const float* Cn_w    = (const float*)d_in[6];
  const float* D_par   = (const float*)d_in[7];
  const float* W_out   = (const float*)d_in[8];
  float* out = (float*)d_out;

  char* ws = (char*)d_ws;
  short* u16   = (short*)(ws + 0);
  short* WtIn  = (short*)(ws + 2097152);
  short* WtOut = (short*)(ws + 11272192);
  float* proj  = (float*)(ws + 15466496);
  float* cosb  = (float*)(ws + 33816576);
  float* sinb  = (float*)(ws + 38010880);
  short* Bb    = (short*)(ws + 42205184);
  short* Cb    = (short*)(ws + 50593792);
  short* xTb   = (short*)(ws + 58982400);
  float* Lcum  = (float*)(ws + 63176704);
  float* u2b   = (float*)(ws + 63307776);
  float* c1b   = (float*)(ws + 63438848);
  short* Hpart = (short*)(ws + 63569920);
  short* Hused = (short*)(ws + 67764224);
  short* yb16  = (short*)(ws + 71958528);   // -> total 76,152,832 B

  prep_inputs<<<3680, 256, 0, stream>>>(u, u16, W_in, WtIn, W_out, WtOut, out);
  gemm1_kernel<<<dim3(28, 8), 256, 0, stream>>>(u16, WtIn, proj);
  scan_theta<<<1056, 256, 0, stream>>>(proj, dt_bias, Lcum, u2b, c1b, cosb, sinb);
  bcxt_kernel<<<1536, 256, 0, stream>>>(proj, B_bias, C_bias, Bn_w, Cn_w, cosb, sinb, Bb, Cb, xTb);
  hpart_kernel<<<256, 256, 0, stream>>>(xTb, Bb, Lcum, u2b, Hpart);
  hscan_kernel<<<1024, 256, 0, stream>>>(Hpart, Lcum, Hused);
  chunky_kernel<<<256, 256, 0, stream>>>(Cb, Bb, xTb, Hused, Lcum, u2b, c1b, proj, D_par, yb16);
  gemm2_kernel<<<dim3(8, 8, 4), 256, 0, stream>>>(yb16, WtOut, out);
}